// Round 5
// baseline (555.580 us; speedup 1.0000x reference)
//
#include <hip/hip_runtime.h>
#include <hip/hip_bf16.h>
#include <stdint.h>

#define S_LEN 2048
#define NB 2
#define NH 16
#define DM 1024
#define KDIM 64
#define MTOK (NB*S_LEN)   // 4096 tokens

typedef __attribute__((ext_vector_type(8))) short bf16x8;
typedef __attribute__((ext_vector_type(4))) float f32x4;
typedef __attribute__((ext_vector_type(4))) unsigned short u16x4;

#define AS1 __attribute__((address_space(1)))
#define AS3 __attribute__((address_space(3)))

__device__ __forceinline__ unsigned short f2bf(float f) {
  unsigned int u = __builtin_bit_cast(unsigned int, f);
  return (unsigned short)((u + 0x7fffu + ((u >> 16) & 1u)) >> 16);   // RNE
}
__device__ __forceinline__ float bf2f(unsigned short h) {
  unsigned int u = ((unsigned int)h) << 16;
  return __builtin_bit_cast(float, u);
}
__device__ __forceinline__ u16x4 pk4bf(float a, float b, float c, float d) {
  union { unsigned u[2]; u16x4 v; } r;
  asm("v_cvt_pk_bf16_f32 %0, %1, %2" : "=v"(r.u[0]) : "v"(a), "v"(b));
  asm("v_cvt_pk_bf16_f32 %0, %1, %2" : "=v"(r.u[1]) : "v"(c), "v"(d));
  return r.v;
}
__device__ __forceinline__ f32x4 mfma16(bf16x8 a, bf16x8 b, f32x4 c) {
  return __builtin_amdgcn_mfma_f32_16x16x32_bf16(a, b, c, 0, 0, 0);
}

// ---------------------------------------------------------------------------
// fp32 -> bf16 convert, 7 segments (q,k,v inputs + Wq,Wk,Wv,Wo)
// ---------------------------------------------------------------------------
struct CvtArgs {
  const float* src[7];
  unsigned short* dst[7];
  int n[7];
};

__global__ __launch_bounds__(256) void cvt_f32_bf16(CvtArgs a) {
  const int seg = blockIdx.y;
  const float* __restrict__ s = a.src[seg];
  unsigned short* __restrict__ d = a.dst[seg];
  const int n4 = a.n[seg] >> 2;
  const int stride = gridDim.x * blockDim.x;
  for (int i = blockIdx.x * blockDim.x + threadIdx.x; i < n4; i += stride) {
    const float4 v = reinterpret_cast<const float4*>(s)[i];
    u16x4 o;
    o[0] = f2bf(v.x); o[1] = f2bf(v.y); o[2] = f2bf(v.z); o[3] = f2bf(v.w);
    reinterpret_cast<u16x4*>(d)[i] = o;
  }
}

// ---------------------------------------------------------------------------
// GEMM: C[m,n] = sum_k A[m,k]*Bw[n,k] + bias[n]   (A,Bw bf16 row-major, K-contig)
// 128x128 tile, BK=32, 4 waves (2x2), global_load_lds width-16 staging.
// ---------------------------------------------------------------------------
template<int MODE>
__global__ __launch_bounds__(256, 2)
void gemm_bt(const unsigned short* __restrict__ A,
             const unsigned short* __restrict__ Bw,
             const float* __restrict__ bias,
             void* __restrict__ dst,
             const int M, const int N, const int K)
{
  __shared__ __align__(16) unsigned short As[128*32];
  __shared__ __align__(16) unsigned short Bs[128*32];
  const int t = threadIdx.x;
  const int w = t >> 6, l = t & 63;
  const int g = l >> 4, cl = l & 15;
  const int m0 = blockIdx.y * 128;
  const int n0 = blockIdx.x * 128;

  const unsigned short* Ag = A + (size_t)(m0 + (t >> 2)) * K + (t & 3) * 8;
  const unsigned short* Bg = Bw + (size_t)(n0 + (t >> 2)) * K + (t & 3) * 8;
  AS3 unsigned short* lA = (AS3 unsigned short*)As + w * 512;
  AS3 unsigned short* lB = (AS3 unsigned short*)Bs + w * 512;

  const int wm = (w >> 1) * 64, wn = (w & 1) * 64;

  f32x4 acc[4][4];
  for (int i = 0; i < 4; ++i) for (int j = 0; j < 4; ++j) acc[i][j] = 0.f;

  for (int kt = 0; kt < K; kt += 32) {
    __builtin_amdgcn_global_load_lds((const AS1 void*)(Ag + kt),                   (AS3 void*)lA,          16, 0, 0);
    __builtin_amdgcn_global_load_lds((const AS1 void*)(Ag + kt + (size_t)64 * K),  (AS3 void*)(lA + 2048), 16, 0, 0);
    __builtin_amdgcn_global_load_lds((const AS1 void*)(Bg + kt),                   (AS3 void*)lB,          16, 0, 0);
    __builtin_amdgcn_global_load_lds((const AS1 void*)(Bg + kt + (size_t)64 * K),  (AS3 void*)(lB + 2048), 16, 0, 0);
    __syncthreads();
    bf16x8 af[4], bfv[4];
    for (int i = 0; i < 4; ++i)
      af[i] = *reinterpret_cast<const bf16x8*>(&As[(wm + 16*i + cl) * 32 + g*8]);
    for (int j = 0; j < 4; ++j)
      bfv[j] = *reinterpret_cast<const bf16x8*>(&Bs[(wn + 16*j + cl) * 32 + g*8]);
    for (int i = 0; i < 4; ++i)
      for (int j = 0; j < 4; ++j)
        acc[i][j] = mfma16(af[i], bfv[j], acc[i][j]);
    __syncthreads();
  }

  for (int i = 0; i < 4; ++i) for (int j = 0; j < 4; ++j) {
    const int ncol = n0 + wn + 16*j + cl;
    const float bn = bias[ncol];
    for (int r = 0; r < 4; ++r) {
      const int m = m0 + wm + 16*i + g*4 + r;
      const float v = acc[i][j][r] + bn;
      if (MODE == 0) {
        const int b = m >> 11, s = m & (S_LEN-1);
        const int h = ncol >> 6, d = ncol & (KDIM-1);
        ((unsigned short*)dst)[((size_t)(b*NH + h)*S_LEN + s)*KDIM + d] = f2bf(v);
      } else if (MODE == 1) {
        const int b = m >> 11, s = m & (S_LEN-1);
        const int h = ncol >> 6, d = ncol & (KDIM-1);
        ((unsigned short*)dst)[((size_t)(b*NH + h)*KDIM + d)*S_LEN + s] = f2bf(v);
      } else {
        ((float*)dst)[(size_t)m * N + ncol] = v;
      }
    }
  }
}

// ---------------------------------------------------------------------------
// Fused attention k1: single QK^T pass per (head, 16-q-row) tile.
// Unnormalized bf16 P -> 64KB LDS (XOR-swizzled); row-sums; PV (V prefetched);
// then LINEAR bf16 P dump to workspace + inv[16] + ctx. No fp32 attn store.
// ---------------------------------------------------------------------------
__global__ __launch_bounds__(256, 2)
void attn_fused5(const unsigned short* __restrict__ Qh,
                 const unsigned short* __restrict__ Kh,
                 const unsigned short* __restrict__ Vt,
                 unsigned short* __restrict__ Pws,
                 float* __restrict__ invws,
                 unsigned short* __restrict__ ctx)
{
  __shared__ __align__(16) unsigned short Pb[16][2048];   // 64 KB, q-major
  __shared__ float statL[4][16];
  auto Obuf = reinterpret_cast<float(*)[16][68]>(&Pb[0][0]);  // overlay after dump

  // bijective XCD swizzle: 4096 = 8*512; XCD x owns heads [4x, 4x+4)
  const int id   = blockIdx.x;
  const int tile = (id & 7) * 512 + (id >> 3);
  const int bh   = tile >> 7;            // 0..31
  const int q0   = (tile & 127) * 16;    // q-tile base within head

  const int t = threadIdx.x, w = t >> 6, l = t & 63;
  const int g = l >> 4, cl = l & 15;
  const int kv0 = w * 512;

  const unsigned short* Qb = Qh + ((size_t)bh * S_LEN + q0) * KDIM;
  const bf16x8 qf0 = *reinterpret_cast<const bf16x8*>(Qb + cl * KDIM + g * 8);
  const bf16x8 qf1 = *reinterpret_cast<const bf16x8*>(Qb + cl * KDIM + 32 + g * 8);

  const unsigned short* Kb = Kh + (size_t)bh * S_LEN * KDIM;
  const unsigned short* Vb = Vt + (size_t)bh * KDIM * S_LEN;
  const float SC2 = 0.125f * 1.44269504f;   // 1/sqrt(64) * log2(e)

  const unsigned xw = (unsigned)((cl & 7) << 4);   // P-tile XOR swizzle (16B granule)
  char* PbRow = (char*)&Pb[0][0] + cl * 4096;      // this lane's q-row (q = cl)

  // ---- single pass: QK^T, exp2 (unnormalized), P->LDS, sums, PV ----
  const unsigned short* Kit = Kb + (size_t)(kv0 + cl) * KDIM + g * 8;
  bf16x8 kA0 = *reinterpret_cast<const bf16x8*>(Kit);
  bf16x8 kA1 = *reinterpret_cast<const bf16x8*>(Kit + 32);
  bf16x8 kB0 = *reinterpret_cast<const bf16x8*>(Kit + 1024);
  bf16x8 kB1 = *reinterpret_cast<const bf16x8*>(Kit + 1024 + 32);

  // V prefetch for first chunk
  bf16x8 vp0, vp1, vp2, vp3;
  {
    const unsigned short* Vp = Vb + (size_t)cl * S_LEN + kv0 + g * 8;
    vp0 = *reinterpret_cast<const bf16x8*>(Vp);
    vp1 = *reinterpret_cast<const bf16x8*>(Vp + 16 * S_LEN);
    vp2 = *reinterpret_cast<const bf16x8*>(Vp + 32 * S_LEN);
    vp3 = *reinterpret_cast<const bf16x8*>(Vp + 48 * S_LEN);
  }

  float sa0 = 0.f, sa1 = 0.f, sa2 = 0.f, sa3 = 0.f;
  f32x4 accP[4];
  for (int dt = 0; dt < 4; ++dt) accP[dt] = 0.f;

  #pragma unroll 2
  for (int s16 = 0; s16 < 32; ++s16) {
    const bf16x8 k0 = kA0, k1 = kA1;
    kA0 = kB0; kA1 = kB1;
    const unsigned short* nxt = Kit + (size_t)(s16 + 2) * 1024;  // ws slack: safe
    kB0 = *reinterpret_cast<const bf16x8*>(nxt);
    kB1 = *reinterpret_cast<const bf16x8*>(nxt + 32);

    f32x4 acc = {0.f, 0.f, 0.f, 0.f};
    acc = mfma16(k0, qf0, acc);
    acc = mfma16(k1, qf1, acc);
    const float p0 = __builtin_exp2f(acc[0] * SC2);
    const float p1 = __builtin_exp2f(acc[1] * SC2);
    const float p2 = __builtin_exp2f(acc[2] * SC2);
    const float p3 = __builtin_exp2f(acc[3] * SC2);
    sa0 += p0; sa1 += p1; sa2 += p2; sa3 += p3;
    const u16x4 pb = pk4bf(p0, p1, p2, p3);
    const unsigned boff = (unsigned)((kv0 + s16 * 16 + g * 4) * 2) ^ xw;
    *reinterpret_cast<u16x4*>(PbRow + boff) = pb;

    if (s16 & 1) {           // 32-kv chunk complete -> PV with prefetched V
      const int ch = kv0 + (s16 - 1) * 16;
      const bf16x8 v0 = vp0, v1 = vp1, v2 = vp2, v3 = vp3;
      {  // prefetch V for next chunk (overread past last chunk is allocated slack)
        const unsigned short* Vp = Vb + (size_t)cl * S_LEN + ch + 32 + g * 8;
        vp0 = *reinterpret_cast<const bf16x8*>(Vp);
        vp1 = *reinterpret_cast<const bf16x8*>(Vp + 16 * S_LEN);
        vp2 = *reinterpret_cast<const bf16x8*>(Vp + 32 * S_LEN);
        vp3 = *reinterpret_cast<const bf16x8*>(Vp + 48 * S_LEN);
      }
      const unsigned aoff = (unsigned)((ch + g * 8) * 2) ^ xw;
      const bf16x8 ap = *reinterpret_cast<const bf16x8*>(PbRow + aoff);
      accP[0] = mfma16(ap, v0, accP[0]);
      accP[1] = mfma16(ap, v1, accP[1]);
      accP[2] = mfma16(ap, v2, accP[2]);
      accP[3] = mfma16(ap, v3, accP[3]);
    }
  }

  float s = (sa0 + sa1) + (sa2 + sa3);   // partial row-sum, q = cl
  s += __shfl_xor(s, 16, 64);
  s += __shfl_xor(s, 32, 64);
  if (l < 16) statL[w][l] = s;
  __syncthreads();                        // P tile + statL complete

  // ---- linear bf16 P dump: wave w dumps rows [w*4, w*4+4) ----
  {
    unsigned short* dtile = Pws + (size_t)tile * 16 * 2048;
    #pragma unroll
    for (int r = 0; r < 4; ++r) {
      const int q = w * 4 + r;
      const unsigned xr = (unsigned)((q & 7) << 4);
      const char* prow = (const char*)&Pb[0][0] + q * 4096;
      char* drow = (char*)(dtile + q * 2048);
      #pragma unroll
      for (int j = 0; j < 4; ++j) {
        const unsigned lin = (unsigned)(j * 1024 + l * 16);
        const bf16x8 pv8 = *reinterpret_cast<const bf16x8*>(prow + (lin ^ xr));
        *reinterpret_cast<bf16x8*>(drow + lin) = pv8;   // fully contiguous 1KB/instr
      }
    }
  }
  if (t < 16)
    invws[tile * 16 + t] =
        1.0f / (statL[0][t] + statL[1][t] + statL[2][t] + statL[3][t]);

  // ---- cross-wave PV reduce via Obuf (overlays Pb after all P reads) ----
  __syncthreads();
  float invr[4];
  #pragma unroll
  for (int r = 0; r < 4; ++r) {
    const int q = g * 4 + r;
    invr[r] = 1.0f / (statL[0][q] + statL[1][q] + statL[2][q] + statL[3][q]);
  }
  #pragma unroll
  for (int dt = 0; dt < 4; ++dt)
    #pragma unroll
    for (int r = 0; r < 4; ++r)
      Obuf[w][g * 4 + r][dt * 16 + cl] = accP[dt][r] * invr[r];
  __syncthreads();
  {
    const int b = bh >> 4, h = bh & 15;
    const int q = t >> 4, d0 = (t & 15) * 4;
    float s0 = 0.f, s1 = 0.f, s2 = 0.f, s3 = 0.f;
    #pragma unroll
    for (int wv = 0; wv < 4; ++wv) {
      const float4 ob = *reinterpret_cast<const float4*>(&Obuf[wv][q][d0]);
      s0 += ob.x; s1 += ob.y; s2 += ob.z; s3 += ob.w;
    }
    u16x4 o;
    o[0] = f2bf(s0); o[1] = f2bf(s1); o[2] = f2bf(s2); o[3] = f2bf(s3);
    *reinterpret_cast<u16x4*>(
        ctx + ((size_t)(b * S_LEN + q0 + q)) * DM + h * KDIM + d0) = o;
  }
}

// ---------------------------------------------------------------------------
// k2: pure streaming expander. Reads bf16 P tile + inv, writes fp32 attn.
// No LDS, no barriers, tiny VGPR -> max occupancy, fillBuffer-like.
// tile is linear: attn flat offset = tile * 16 * 2048.
// ---------------------------------------------------------------------------
__global__ __launch_bounds__(256)
void attn_expand(const unsigned short* __restrict__ Pws,
                 const float* __restrict__ invws,
                 float* __restrict__ attn)
{
  const int tile = blockIdx.x;           // 0..4095
  const int t = threadIdx.x;
  const unsigned short* src = Pws + (size_t)tile * 16 * 2048;
  float* dst = attn + (size_t)tile * 16 * 2048;
  const float* invp = invws + tile * 16;

  #pragma unroll 4
  for (int r = 0; r < 16; ++r) {
    const float inv = invp[r];
    const unsigned short* s = src + r * 2048 + t * 4;
    float* d = dst + r * 2048 + t * 4;
    #pragma unroll
    for (int i = 0; i < 2; ++i) {
      const u16x4 v = *reinterpret_cast<const u16x4*>(s + i * 1024);
      f32x4 o;
      o[0] = bf2f(v[0]) * inv; o[1] = bf2f(v[1]) * inv;
      o[2] = bf2f(v[2]) * inv; o[3] = bf2f(v[3]) * inv;
      *reinterpret_cast<f32x4*>(d + i * 1024) = o;
    }
  }
}

// ---------------------------------------------------------------------------
extern "C" void kernel_launch(void* const* d_in, const int* in_sizes, int n_in,
                              void* d_out, int out_size, void* d_ws, size_t ws_size,
                              hipStream_t stream)
{
  const float* q_in = (const float*)d_in[0];
  const float* k_in = (const float*)d_in[1];
  const float* v_in = (const float*)d_in[2];
  const float* Wq   = (const float*)d_in[3];
  const float* bq   = (const float*)d_in[4];
  const float* Wk   = (const float*)d_in[5];
  const float* bk   = (const float*)d_in[6];
  const float* Wv   = (const float*)d_in[7];
  const float* bv   = (const float*)d_in[8];
  const float* Wo   = (const float*)d_in[9];
  const float* bo   = (const float*)d_in[10];

  unsigned short* qbf  = (unsigned short*)d_ws;
  unsigned short* kbf  = qbf  + (size_t)MTOK*DM;
  unsigned short* vbf  = kbf  + (size_t)MTOK*DM;
  unsigned short* wqbf = vbf  + (size_t)MTOK*DM;
  unsigned short* wkbf = wqbf + (size_t)DM*DM;
  unsigned short* wvbf = wkbf + (size_t)DM*DM;
  unsigned short* wobf = wvbf + (size_t)DM*DM;
  unsigned short* Qhp  = wobf + (size_t)DM*DM;    // [b,h,s,d]
  unsigned short* Khp  = Qhp  + (size_t)MTOK*DM;  // [b,h,s,d]
  unsigned short* Vtp  = Khp  + (size_t)MTOK*DM;  // [b,h,d,s]
  unsigned short* ctx  = Vtp  + (size_t)MTOK*DM;  // [b*s, h*d]
  unsigned short* Pws  = ctx  + (size_t)MTOK*DM;  // [4096 tiles][16][2048] bf16
  float*          invws = (float*)(Pws + (size_t)4096 * 16 * 2048);  // [4096][16]

  float* out0 = (float*)d_out;
  float* attn = out0 + (size_t)MTOK*DM;

  CvtArgs ca;
  ca.src[0] = q_in; ca.dst[0] = qbf;  ca.n[0] = MTOK*DM;
  ca.src[1] = k_in; ca.dst[1] = kbf;  ca.n[1] = MTOK*DM;
  ca.src[2] = v_in; ca.dst[2] = vbf;  ca.n[2] = MTOK*DM;
  ca.src[3] = Wq;   ca.dst[3] = wqbf; ca.n[3] = DM*DM;
  ca.src[4] = Wk;   ca.dst[4] = wkbf; ca.n[4] = DM*DM;
  ca.src[5] = Wv;   ca.dst[5] = wvbf; ca.n[5] = DM*DM;
  ca.src[6] = Wo;   ca.dst[6] = wobf; ca.n[6] = DM*DM;
  cvt_f32_bf16<<<dim3(512, 7), 256, 0, stream>>>(ca);

  gemm_bt<0><<<dim3(8, 32), 256, 0, stream>>>(qbf, wqbf, bq, Qhp, MTOK, DM, DM);
  gemm_bt<0><<<dim3(8, 32), 256, 0, stream>>>(kbf, wkbf, bk, Khp, MTOK, DM, DM);
  gemm_bt<1><<<dim3(8, 32), 256, 0, stream>>>(vbf, wvbf, bv, Vtp, MTOK, DM, DM);

  attn_fused5<<<dim3(4096), 256, 0, stream>>>(Qhp, Khp, Vtp, Pws, invws, ctx);
  attn_expand<<<dim3(4096), 256, 0, stream>>>(Pws, invws, attn);

  gemm_bt<2><<<dim3(8, 32), 256, 0, stream>>>(ctx, wobf, bo, (void*)out0, MTOK, DM, DM);
}

// Round 6
// 481.323 us; speedup vs baseline: 1.1543x; 1.1543x over previous
//
#include <hip/hip_runtime.h>
#include <hip/hip_bf16.h>
#include <stdint.h>

#define S_LEN 2048
#define NB 2
#define NH 16
#define DM 1024
#define KDIM 64
#define MTOK (NB*S_LEN)   // 4096 tokens

typedef __attribute__((ext_vector_type(8))) short bf16x8;
typedef __attribute__((ext_vector_type(4))) float f32x4;
typedef __attribute__((ext_vector_type(4))) unsigned short u16x4;

#define AS1 __attribute__((address_space(1)))
#define AS3 __attribute__((address_space(3)))

__device__ __forceinline__ unsigned short f2bf(float f) {
  unsigned int u = __builtin_bit_cast(unsigned int, f);
  return (unsigned short)((u + 0x7fffu + ((u >> 16) & 1u)) >> 16);   // RNE
}
__device__ __forceinline__ float bf2f(unsigned short h) {
  unsigned int u = ((unsigned int)h) << 16;
  return __builtin_bit_cast(float, u);
}
__device__ __forceinline__ f32x4 mfma16(bf16x8 a, bf16x8 b, f32x4 c) {
  return __builtin_amdgcn_mfma_f32_16x16x32_bf16(a, b, c, 0, 0, 0);
}

// ---------------------------------------------------------------------------
// fp32 -> bf16 convert, 7 segments (q,k,v inputs + Wq,Wk,Wv,Wo)
// ---------------------------------------------------------------------------
struct CvtArgs {
  const float* src[7];
  unsigned short* dst[7];
  int n[7];
};

__global__ __launch_bounds__(256) void cvt_f32_bf16(CvtArgs a) {
  const int seg = blockIdx.y;
  const float* __restrict__ s = a.src[seg];
  unsigned short* __restrict__ d = a.dst[seg];
  const int n4 = a.n[seg] >> 2;
  const int stride = gridDim.x * blockDim.x;
  for (int i = blockIdx.x * blockDim.x + threadIdx.x; i < n4; i += stride) {
    const float4 v = reinterpret_cast<const float4*>(s)[i];
    u16x4 o;
    o[0] = f2bf(v.x); o[1] = f2bf(v.y); o[2] = f2bf(v.z); o[3] = f2bf(v.w);
    reinterpret_cast<u16x4*>(d)[i] = o;
  }
}

// ---------------------------------------------------------------------------
// GEMM: C[m,n] = sum_k A[m,k]*Bw[n,k] + bias[n]   (A,Bw bf16 row-major, K-contig)
// 128x128 tile, BK=32, 4 waves (2x2), global_load_lds width-16 staging.
// ---------------------------------------------------------------------------
template<int MODE>
__global__ __launch_bounds__(256, 2)
void gemm_bt(const unsigned short* __restrict__ A,
             const unsigned short* __restrict__ Bw,
             const float* __restrict__ bias,
             void* __restrict__ dst,
             const int M, const int N, const int K)
{
  __shared__ __align__(16) unsigned short As[128*32];
  __shared__ __align__(16) unsigned short Bs[128*32];
  const int t = threadIdx.x;
  const int w = t >> 6, l = t & 63;
  const int g = l >> 4, cl = l & 15;
  const int m0 = blockIdx.y * 128;
  const int n0 = blockIdx.x * 128;

  const unsigned short* Ag = A + (size_t)(m0 + (t >> 2)) * K + (t & 3) * 8;
  const unsigned short* Bg = Bw + (size_t)(n0 + (t >> 2)) * K + (t & 3) * 8;
  AS3 unsigned short* lA = (AS3 unsigned short*)As + w * 512;
  AS3 unsigned short* lB = (AS3 unsigned short*)Bs + w * 512;

  const int wm = (w >> 1) * 64, wn = (w & 1) * 64;

  f32x4 acc[4][4];
  for (int i = 0; i < 4; ++i) for (int j = 0; j < 4; ++j) acc[i][j] = 0.f;

  for (int kt = 0; kt < K; kt += 32) {
    __builtin_amdgcn_global_load_lds((const AS1 void*)(Ag + kt),                   (AS3 void*)lA,          16, 0, 0);
    __builtin_amdgcn_global_load_lds((const AS1 void*)(Ag + kt + (size_t)64 * K),  (AS3 void*)(lA + 2048), 16, 0, 0);
    __builtin_amdgcn_global_load_lds((const AS1 void*)(Bg + kt),                   (AS3 void*)lB,          16, 0, 0);
    __builtin_amdgcn_global_load_lds((const AS1 void*)(Bg + kt + (size_t)64 * K),  (AS3 void*)(lB + 2048), 16, 0, 0);
    __syncthreads();
    bf16x8 af[4], bfv[4];
    for (int i = 0; i < 4; ++i)
      af[i] = *reinterpret_cast<const bf16x8*>(&As[(wm + 16*i + cl) * 32 + g*8]);
    for (int j = 0; j < 4; ++j)
      bfv[j] = *reinterpret_cast<const bf16x8*>(&Bs[(wn + 16*j + cl) * 32 + g*8]);
    for (int i = 0; i < 4; ++i)
      for (int j = 0; j < 4; ++j)
        acc[i][j] = mfma16(af[i], bfv[j], acc[i][j]);
    __syncthreads();
  }

  for (int i = 0; i < 4; ++i) for (int j = 0; j < 4; ++j) {
    const int ncol = n0 + wn + 16*j + cl;
    const float bn = bias[ncol];
    for (int r = 0; r < 4; ++r) {
      const int m = m0 + wm + 16*i + g*4 + r;
      const float v = acc[i][j][r] + bn;
      if (MODE == 0) {
        const int b = m >> 11, s = m & (S_LEN-1);
        const int h = ncol >> 6, d = ncol & (KDIM-1);
        ((unsigned short*)dst)[((size_t)(b*NH + h)*S_LEN + s)*KDIM + d] = f2bf(v);
      } else if (MODE == 1) {
        const int b = m >> 11, s = m & (S_LEN-1);
        const int h = ncol >> 6, d = ncol & (KDIM-1);
        ((unsigned short*)dst)[((size_t)(b*NH + h)*KDIM + d)*S_LEN + s] = f2bf(v);
      } else {
        ((float*)dst)[(size_t)m * N + ncol] = v;
      }
    }
  }
}

// ---------------------------------------------------------------------------
// Fused attention v6: 512-thread blocks, 8 waves, each owns a 256-kv strip of
// one 16-q-row tile. Single QK^T pass, unnormalized bf16 P -> 64KB LDS
// (XOR-swizzled), row sums + PV partials via LDS atomics, then decoupled
// fp32 attn store (8 waves x 2 rows) + ctx write. 2 blocks/CU = 16 waves/CU.
// ---------------------------------------------------------------------------
__global__ __launch_bounds__(512, 4)
void attn_fused6(const unsigned short* __restrict__ Qh,
                 const unsigned short* __restrict__ Kh,
                 const unsigned short* __restrict__ Vt,
                 float* __restrict__ attn,
                 unsigned short* __restrict__ ctx)
{
  __shared__ __align__(16) unsigned short Pb[16][2048];   // 64 KB, q-major
  __shared__ float Obuf[16][68];                          // PV accum (atomic)
  __shared__ float statS[16];                             // row sums (atomic)

  // bijective XCD swizzle: 4096 = 8*512; XCD x owns heads [4x, 4x+4)
  const int id   = blockIdx.x;
  const int tile = (id & 7) * 512 + (id >> 3);
  const int bh   = tile >> 7;            // 0..31
  const int q0   = (tile & 127) * 16;    // q-tile base within head

  const int t = threadIdx.x, w = t >> 6, l = t & 63;
  const int g = l >> 4, cl = l & 15;
  const int kv0 = w * 256;

  // zero accumulators, then one barrier before any atomics
  if (t < 16) statS[t] = 0.f;
  for (int i = t; i < 16 * 68; i += 512) (&Obuf[0][0])[i] = 0.f;

  const unsigned short* Qb = Qh + ((size_t)bh * S_LEN + q0) * KDIM;
  const bf16x8 qf0 = *reinterpret_cast<const bf16x8*>(Qb + cl * KDIM + g * 8);
  const bf16x8 qf1 = *reinterpret_cast<const bf16x8*>(Qb + cl * KDIM + 32 + g * 8);

  const unsigned short* Kb = Kh + (size_t)bh * S_LEN * KDIM;
  const unsigned short* Vb = Vt + (size_t)bh * KDIM * S_LEN;
  const float SC2 = 0.125f * 1.44269504f;   // 1/sqrt(64) * log2(e)

  const unsigned xw = (unsigned)((cl & 7) << 4);   // P-tile XOR swizzle
  char* PbRow = (char*)&Pb[0][0] + cl * 4096;      // this lane's q-row (q = cl)

  __syncthreads();                                 // init visible to all

  // ---- main pass: QK^T, exp2 (unnormalized), P->LDS, sums, PV ----
  const unsigned short* Kit = Kb + (size_t)(kv0 + cl) * KDIM + g * 8;
  bf16x8 kA0 = *reinterpret_cast<const bf16x8*>(Kit);
  bf16x8 kA1 = *reinterpret_cast<const bf16x8*>(Kit + 32);
  bf16x8 kB0 = *reinterpret_cast<const bf16x8*>(Kit + 1024);
  bf16x8 kB1 = *reinterpret_cast<const bf16x8*>(Kit + 1024 + 32);

  bf16x8 vp0, vp1, vp2, vp3;
  {
    const unsigned short* Vp = Vb + (size_t)cl * S_LEN + kv0 + g * 8;
    vp0 = *reinterpret_cast<const bf16x8*>(Vp);
    vp1 = *reinterpret_cast<const bf16x8*>(Vp + 16 * S_LEN);
    vp2 = *reinterpret_cast<const bf16x8*>(Vp + 32 * S_LEN);
    vp3 = *reinterpret_cast<const bf16x8*>(Vp + 48 * S_LEN);
  }

  float sa0 = 0.f, sa1 = 0.f, sa2 = 0.f, sa3 = 0.f;
  f32x4 accP[4];
  for (int dt = 0; dt < 4; ++dt) accP[dt] = 0.f;

  #pragma unroll 2
  for (int s16 = 0; s16 < 16; ++s16) {
    const bf16x8 k0 = kA0, k1 = kA1;
    kA0 = kB0; kA1 = kB1;
    const unsigned short* nxt = Kit + (size_t)(s16 + 2) * 1024;  // ws slack: safe
    kB0 = *reinterpret_cast<const bf16x8*>(nxt);
    kB1 = *reinterpret_cast<const bf16x8*>(nxt + 32);

    f32x4 acc = {0.f, 0.f, 0.f, 0.f};
    acc = mfma16(k0, qf0, acc);
    acc = mfma16(k1, qf1, acc);
    const float p0 = __builtin_exp2f(acc[0] * SC2);
    const float p1 = __builtin_exp2f(acc[1] * SC2);
    const float p2 = __builtin_exp2f(acc[2] * SC2);
    const float p3 = __builtin_exp2f(acc[3] * SC2);
    sa0 += p0; sa1 += p1; sa2 += p2; sa3 += p3;
    u16x4 pb;
    pb[0] = f2bf(p0); pb[1] = f2bf(p1); pb[2] = f2bf(p2); pb[3] = f2bf(p3);
    const unsigned boff = (unsigned)((kv0 + s16 * 16 + g * 4) * 2) ^ xw;
    *reinterpret_cast<u16x4*>(PbRow + boff) = pb;

    if (s16 & 1) {           // 32-kv chunk complete -> PV with prefetched V
      const int ch = kv0 + (s16 - 1) * 16;
      const bf16x8 v0 = vp0, v1 = vp1, v2 = vp2, v3 = vp3;
      {  // prefetch next chunk (overread past strip end lands in valid ws)
        const unsigned short* Vp = Vb + (size_t)cl * S_LEN + ch + 32 + g * 8;
        vp0 = *reinterpret_cast<const bf16x8*>(Vp);
        vp1 = *reinterpret_cast<const bf16x8*>(Vp + 16 * S_LEN);
        vp2 = *reinterpret_cast<const bf16x8*>(Vp + 32 * S_LEN);
        vp3 = *reinterpret_cast<const bf16x8*>(Vp + 48 * S_LEN);
      }
      const unsigned aoff = (unsigned)((ch + g * 8) * 2) ^ xw;
      const bf16x8 ap = *reinterpret_cast<const bf16x8*>(PbRow + aoff);
      accP[0] = mfma16(ap, v0, accP[0]);
      accP[1] = mfma16(ap, v1, accP[1]);
      accP[2] = mfma16(ap, v2, accP[2]);
      accP[3] = mfma16(ap, v3, accP[3]);
    }
  }

  // row-sum partial (strip): all lanes hold row-cl sum after shuffles
  float s = (sa0 + sa1) + (sa2 + sa3);
  s += __shfl_xor(s, 16, 64);
  s += __shfl_xor(s, 32, 64);
  if (l < 16) atomicAdd(&statS[l], s);

  // PV partials -> Obuf via LDS atomics (q = g*4+r, d = dt*16+cl)
  #pragma unroll
  for (int dt = 0; dt < 4; ++dt)
    #pragma unroll
    for (int r = 0; r < 4; ++r)
      atomicAdd(&Obuf[g * 4 + r][dt * 16 + cl], accP[dt][r]);

  __syncthreads();                        // P tile, statS, Obuf complete

  // ---- ctx write (first 256 threads) ----
  if (t < 256) {
    const int b = bh >> 4, h = bh & 15;
    const int q = t >> 4, d0 = (t & 15) * 4;
    const float invq = 1.0f / statS[q];
    u16x4 o;
    o[0] = f2bf(Obuf[q][d0 + 0] * invq);
    o[1] = f2bf(Obuf[q][d0 + 1] * invq);
    o[2] = f2bf(Obuf[q][d0 + 2] * invq);
    o[3] = f2bf(Obuf[q][d0 + 3] * invq);
    *reinterpret_cast<u16x4*>(
        ctx + ((size_t)(b * S_LEN + q0 + q)) * DM + h * KDIM + d0) = o;
  }

  // ---- decoupled store phase: wave w streams rows {2w, 2w+1} ----
  #pragma unroll
  for (int rr = 0; rr < 2; ++rr) {
    const int q = w * 2 + rr;
    const float invq = 1.0f / statS[q];
    float* arow = attn + ((size_t)bh * S_LEN + q0 + q) * S_LEN;
    const unsigned xr = (unsigned)((q & 7) << 4);
    const char* prow = (const char*)&Pb[0][0] + q * 4096;
    #pragma unroll
    for (int j = 0; j < 4; ++j) {
      const unsigned lin = (unsigned)(j * 1024 + l * 16);
      const bf16x8 pv8 = *reinterpret_cast<const bf16x8*>(prow + (lin ^ xr));
      f32x4 o0, o1;
      #pragma unroll
      for (int i = 0; i < 4; ++i) {
        o0[i] = bf2f((unsigned short)pv8[i]) * invq;
        o1[i] = bf2f((unsigned short)pv8[4 + i]) * invq;
      }
      float* dstp = arow + j * 512 + l * 8;
      *reinterpret_cast<f32x4*>(dstp) = o0;
      *reinterpret_cast<f32x4*>(dstp + 4) = o1;
    }
  }
}

// ---------------------------------------------------------------------------
extern "C" void kernel_launch(void* const* d_in, const int* in_sizes, int n_in,
                              void* d_out, int out_size, void* d_ws, size_t ws_size,
                              hipStream_t stream)
{
  const float* q_in = (const float*)d_in[0];
  const float* k_in = (const float*)d_in[1];
  const float* v_in = (const float*)d_in[2];
  const float* Wq   = (const float*)d_in[3];
  const float* bq   = (const float*)d_in[4];
  const float* Wk   = (const float*)d_in[5];
  const float* bk   = (const float*)d_in[6];
  const float* Wv   = (const float*)d_in[7];
  const float* bv   = (const float*)d_in[8];
  const float* Wo   = (const float*)d_in[9];
  const float* bo   = (const float*)d_in[10];

  unsigned short* qbf  = (unsigned short*)d_ws;
  unsigned short* kbf  = qbf  + (size_t)MTOK*DM;
  unsigned short* vbf  = kbf  + (size_t)MTOK*DM;
  unsigned short* wqbf = vbf  + (size_t)MTOK*DM;
  unsigned short* wkbf = wqbf + (size_t)DM*DM;
  unsigned short* wvbf = wkbf + (size_t)DM*DM;
  unsigned short* wobf = wvbf + (size_t)DM*DM;
  unsigned short* Qhp  = wobf + (size_t)DM*DM;    // [b,h,s,d]
  unsigned short* Khp  = Qhp  + (size_t)MTOK*DM;  // [b,h,s,d]
  unsigned short* Vtp  = Khp  + (size_t)MTOK*DM;  // [b,h,d,s]
  unsigned short* ctx  = Vtp  + (size_t)MTOK*DM;  // [b*s, h*d]

  float* out0 = (float*)d_out;
  float* attn = out0 + (size_t)MTOK*DM;

  CvtArgs ca;
  ca.src[0] = q_in; ca.dst[0] = qbf;  ca.n[0] = MTOK*DM;
  ca.src[1] = k_in; ca.dst[1] = kbf;  ca.n[1] = MTOK*DM;
  ca.src[2] = v_in; ca.dst[2] = vbf;  ca.n[2] = MTOK*DM;
  ca.src[3] = Wq;   ca.dst[3] = wqbf; ca.n[3] = DM*DM;
  ca.src[4] = Wk;   ca.dst[4] = wkbf; ca.n[4] = DM*DM;
  ca.src[5] = Wv;   ca.dst[5] = wvbf; ca.n[5] = DM*DM;
  ca.src[6] = Wo;   ca.dst[6] = wobf; ca.n[6] = DM*DM;
  cvt_f32_bf16<<<dim3(512, 7), 256, 0, stream>>>(ca);

  gemm_bt<0><<<dim3(8, 32), 256, 0, stream>>>(qbf, wqbf, bq, Qhp, MTOK, DM, DM);
  gemm_bt<0><<<dim3(8, 32), 256, 0, stream>>>(kbf, wkbf, bk, Khp, MTOK, DM, DM);
  gemm_bt<1><<<dim3(8, 32), 256, 0, stream>>>(vbf, wvbf, bv, Vtp, MTOK, DM, DM);

  attn_fused6<<<dim3(4096), 512, 0, stream>>>(Qhp, Khp, Vtp, attn, ctx);

  gemm_bt<2><<<dim3(8, 32), 256, 0, stream>>>(ctx, wobf, bo, (void*)out0, MTOK, DM, DM);
}

// Round 7
// 342.728 us; speedup vs baseline: 1.6211x; 1.4044x over previous
//
#include <hip/hip_runtime.h>
#include <hip/hip_bf16.h>
#include <stdint.h>

#define S_LEN 2048
#define NB 2
#define NH 16
#define DM 1024
#define KDIM 64
#define MTOK (NB*S_LEN)   // 4096 tokens

typedef __attribute__((ext_vector_type(8))) short bf16x8;
typedef __attribute__((ext_vector_type(4))) float f32x4;
typedef __attribute__((ext_vector_type(4))) unsigned short u16x4;

#define AS1 __attribute__((address_space(1)))
#define AS3 __attribute__((address_space(3)))

__device__ __forceinline__ unsigned short f2bf(float f) {
  unsigned int u = __builtin_bit_cast(unsigned int, f);
  return (unsigned short)((u + 0x7fffu + ((u >> 16) & 1u)) >> 16);   // RNE
}
__device__ __forceinline__ f32x4 mfma16(bf16x8 a, bf16x8 b, f32x4 c) {
  return __builtin_amdgcn_mfma_f32_16x16x32_bf16(a, b, c, 0, 0, 0);
}

// ---------------------------------------------------------------------------
// fp32 -> bf16 convert, 7 segments (q,k,v inputs + Wq,Wk,Wv,Wo)
// ---------------------------------------------------------------------------
struct CvtArgs {
  const float* src[7];
  unsigned short* dst[7];
  int n[7];
};

__global__ __launch_bounds__(256) void cvt_f32_bf16(CvtArgs a) {
  const int seg = blockIdx.y;
  const float* __restrict__ s = a.src[seg];
  unsigned short* __restrict__ d = a.dst[seg];
  const int n4 = a.n[seg] >> 2;
  const int stride = gridDim.x * blockDim.x;
  for (int i = blockIdx.x * blockDim.x + threadIdx.x; i < n4; i += stride) {
    const float4 v = reinterpret_cast<const float4*>(s)[i];
    u16x4 o;
    o[0] = f2bf(v.x); o[1] = f2bf(v.y); o[2] = f2bf(v.z); o[3] = f2bf(v.w);
    reinterpret_cast<u16x4*>(d)[i] = o;
  }
}

// ---------------------------------------------------------------------------
// GEMM: C[m,n] = sum_k A[m,k]*Bw[n,k] + bias[n]   (A,Bw bf16 row-major, K-contig)
// 128x128 tile, BK=32, 4 waves (2x2), global_load_lds width-16 staging.
// ---------------------------------------------------------------------------
template<int MODE>
__global__ __launch_bounds__(256, 2)
void gemm_bt(const unsigned short* __restrict__ A,
             const unsigned short* __restrict__ Bw,
             const float* __restrict__ bias,
             void* __restrict__ dst,
             const int M, const int N, const int K)
{
  __shared__ __align__(16) unsigned short As[128*32];
  __shared__ __align__(16) unsigned short Bs[128*32];
  const int t = threadIdx.x;
  const int w = t >> 6, l = t & 63;
  const int g = l >> 4, cl = l & 15;
  const int m0 = blockIdx.y * 128;
  const int n0 = blockIdx.x * 128;

  const unsigned short* Ag = A + (size_t)(m0 + (t >> 2)) * K + (t & 3) * 8;
  const unsigned short* Bg = Bw + (size_t)(n0 + (t >> 2)) * K + (t & 3) * 8;
  AS3 unsigned short* lA = (AS3 unsigned short*)As + w * 512;
  AS3 unsigned short* lB = (AS3 unsigned short*)Bs + w * 512;

  const int wm = (w >> 1) * 64, wn = (w & 1) * 64;

  f32x4 acc[4][4];
  for (int i = 0; i < 4; ++i) for (int j = 0; j < 4; ++j) acc[i][j] = 0.f;

  for (int kt = 0; kt < K; kt += 32) {
    __builtin_amdgcn_global_load_lds((const AS1 void*)(Ag + kt),                   (AS3 void*)lA,          16, 0, 0);
    __builtin_amdgcn_global_load_lds((const AS1 void*)(Ag + kt + (size_t)64 * K),  (AS3 void*)(lA + 2048), 16, 0, 0);
    __builtin_amdgcn_global_load_lds((const AS1 void*)(Bg + kt),                   (AS3 void*)lB,          16, 0, 0);
    __builtin_amdgcn_global_load_lds((const AS1 void*)(Bg + kt + (size_t)64 * K),  (AS3 void*)(lB + 2048), 16, 0, 0);
    __syncthreads();
    bf16x8 af[4], bfv[4];
    for (int i = 0; i < 4; ++i)
      af[i] = *reinterpret_cast<const bf16x8*>(&As[(wm + 16*i + cl) * 32 + g*8]);
    for (int j = 0; j < 4; ++j)
      bfv[j] = *reinterpret_cast<const bf16x8*>(&Bs[(wn + 16*j + cl) * 32 + g*8]);
    for (int i = 0; i < 4; ++i)
      for (int j = 0; j < 4; ++j)
        acc[i][j] = mfma16(af[i], bfv[j], acc[i][j]);
    __syncthreads();
  }

  for (int i = 0; i < 4; ++i) for (int j = 0; j < 4; ++j) {
    const int ncol = n0 + wn + 16*j + cl;
    const float bn = bias[ncol];
    for (int r = 0; r < 4; ++r) {
      const int m = m0 + wm + 16*i + g*4 + r;
      const float v = acc[i][j][r] + bn;
      if (MODE == 0) {
        const int b = m >> 11, s = m & (S_LEN-1);
        const int h = ncol >> 6, d = ncol & (KDIM-1);
        ((unsigned short*)dst)[((size_t)(b*NH + h)*S_LEN + s)*KDIM + d] = f2bf(v);
      } else if (MODE == 1) {
        const int b = m >> 11, s = m & (S_LEN-1);
        const int h = ncol >> 6, d = ncol & (KDIM-1);
        ((unsigned short*)dst)[((size_t)(b*NH + h)*KDIM + d)*S_LEN + s] = f2bf(v);
      } else {
        ((float*)dst)[(size_t)m * N + ncol] = v;
      }
    }
  }
}

// ---------------------------------------------------------------------------
// Fused attention v7: block = 128 q-rows x all 2048 kv; 8 waves x 16 rows
// (no cross-wave reduction). K/V staged in LDS: 8 buffers, stage 6 ahead,
// hand-counted vmcnt so stores are NEVER drained by a load-wait.
// Pass A: QK^T + exp sums + PV (no global stores). Pass B: recompute from
// LDS K, normalize, stream fp32 attn (waves 4-7 execute zero vmcnt waits).
// ---------------------------------------------------------------------------
__global__ __launch_bounds__(512, 4)
void attn_fused7(const unsigned short* __restrict__ Qh,
                 const unsigned short* __restrict__ Kh,
                 const unsigned short* __restrict__ Vt,
                 float* __restrict__ attn,
                 unsigned short* __restrict__ ctx)
{
  // LDS: K bufs 8x4096 (chunk [32 kv][64 d], 16B-granule XOR-swizzled by kv&7)
  //      V bufs 8x4096 (chunk [64 d][32 kv], granule swizzled by (d&3)^((d>>2)&3))
  //      P bounce 8 waves x [16 q][40 u16] (80B rows)
  __shared__ __align__(16) char smem[75776];
  AS3 char* const KB = (AS3 char*)smem;
  AS3 char* const VB = (AS3 char*)smem + 32768;

  const int id  = blockIdx.x;                 // 512 blocks = 8 XCD x 64
  const int swz = (id & 7) * 64 + (id >> 3);  // bijective XCD swizzle
  const int bh  = swz >> 4;                   // head 0..31
  const int q0  = (swz & 15) * 128;           // 128-row q tile

  const int t = threadIdx.x, w = t >> 6, l = t & 63;
  const int g = l >> 4, cl = l & 15;
  AS3 char* const PBw = (AS3 char*)smem + 65536 + w * 1280;
  const int b = bh >> 4, h = bh & 15;

  // Q fragments: this lane's q-row = q0 + w*16 + cl
  const unsigned short* Qb = Qh + ((size_t)bh * S_LEN + q0 + w*16 + cl) * KDIM;
  const bf16x8 qf0 = *reinterpret_cast<const bf16x8*>(Qb + g*8);
  const bf16x8 qf1 = *reinterpret_cast<const bf16x8*>(Qb + 32 + g*8);

  // per-lane staging sources (pre-swizzled global addresses; LDS dest linear)
  const int rs = (w & 3)*8 + (l >> 3), js = l & 7;          // K: row in chunk, granule
  const unsigned short* pK = Kh + (size_t)bh*S_LEN*KDIM + (size_t)rs*KDIM
                                + (size_t)((js ^ (rs & 7)) * 8);
  const int dsv = (w & 3)*16 + (l >> 2), jv = l & 3;        // V: d-row, granule
  const int kst = (dsv & 3) ^ ((dsv >> 2) & 3);
  const unsigned short* pV = Vt + (size_t)bh*KDIM*S_LEN + (size_t)dsv*S_LEN
                                + (size_t)((jv ^ kst) * 8);

  const unsigned kvkey = (unsigned)((cl & 3) ^ ((cl >> 2) & 3));
  const unsigned koff0 = (unsigned)(cl*128 + ((g ^ (cl & 7)) << 4));
  const unsigned koff1 = (unsigned)(cl*128 + (((g + 4) ^ (cl & 7)) << 4));
  const float SC2 = 0.125f * 1.44269504f;     // 1/sqrt(64) * log2(e)

  #define STAGE_KV(ch) do { int _b = (ch) & 7;                                              \
    if (w < 4) __builtin_amdgcn_global_load_lds((const AS1 void*)(pK + (size_t)(ch)*2048),  \
                   (AS3 void*)(KB + _b*4096 + (w&3)*1024), 16, 0, 0);                       \
    else       __builtin_amdgcn_global_load_lds((const AS1 void*)(pV + (size_t)(ch)*32),    \
                   (AS3 void*)(VB + _b*4096 + (w&3)*1024), 16, 0, 0); } while (0)
  #define STAGE_K(ch) do { int _b = (ch) & 7;                                               \
    if (w < 4) __builtin_amdgcn_global_load_lds((const AS1 void*)(pK + (size_t)(ch)*2048),  \
                   (AS3 void*)(KB + _b*4096 + (w&3)*1024), 16, 0, 0); } while (0)

  // ================= PASS A: sums + PV (no global stores) =================
  float sa0 = 0.f, sa1 = 0.f, sa2 = 0.f, sa3 = 0.f;
  f32x4 accP[4];
  #pragma unroll
  for (int dt = 0; dt < 4; ++dt) accP[dt] = 0.f;

  for (int i = 0; i < 6; ++i) STAGE_KV(i);
  for (int c = 0; c < 64; ++c) {
    STAGE_KV(c + 6);                             // overrun reads land in valid ws
    asm volatile("s_waitcnt vmcnt(6)" ::: "memory");
    __builtin_amdgcn_s_barrier();
    __builtin_amdgcn_sched_barrier(0);
    AS3 const char* kb = KB + (c & 7) * 4096;
    AS3 const char* vb = VB + (c & 7) * 4096;
    #pragma unroll
    for (int s = 0; s < 2; ++s) {
      const bf16x8 k0 = *(const AS3 bf16x8*)(kb + s*2048 + koff0);
      const bf16x8 k1 = *(const AS3 bf16x8*)(kb + s*2048 + koff1);
      f32x4 acc = {0.f, 0.f, 0.f, 0.f};
      acc = mfma16(k0, qf0, acc);
      acc = mfma16(k1, qf1, acc);
      const float p0 = __builtin_exp2f(acc[0] * SC2);
      const float p1 = __builtin_exp2f(acc[1] * SC2);
      const float p2 = __builtin_exp2f(acc[2] * SC2);
      const float p3 = __builtin_exp2f(acc[3] * SC2);
      sa0 += p0; sa1 += p1; sa2 += p2; sa3 += p3;
      u16x4 pb;
      pb[0] = f2bf(p0); pb[1] = f2bf(p1); pb[2] = f2bf(p2); pb[3] = f2bf(p3);
      *(AS3 u16x4*)(PBw + cl*80 + s*32 + g*8) = pb;
    }
    const bf16x8 ap = *(const AS3 bf16x8*)(PBw + cl*80 + g*16);
    #pragma unroll
    for (int dt = 0; dt < 4; ++dt) {
      const bf16x8 bv = *(const AS3 bf16x8*)(vb + (dt*16 + cl)*64 + ((g ^ kvkey) << 4));
      accP[dt] = mfma16(ap, bv, accP[dt]);
    }
  }

  // row sums (own rows only — no cross-wave combine needed)
  float ssum = (sa0 + sa1) + (sa2 + sa3);
  ssum += __shfl_xor(ssum, 16, 64);
  ssum += __shfl_xor(ssum, 32, 64);
  const float inv = 1.0f / ssum;                 // row q = cl (all lanes)

  // ctx write: lane holds O[q = g*4+r][d = dt*16+cl]
  #pragma unroll
  for (int r = 0; r < 4; ++r) {
    const float invq = __shfl(inv, g*4 + r, 64);
    const size_t row = (size_t)(b * S_LEN + q0 + w*16 + g*4 + r);
    #pragma unroll
    for (int dt = 0; dt < 4; ++dt)
      ctx[row * DM + h * KDIM + dt*16 + cl] = f2bf(accP[dt][r] * invq);
  }

  __syncthreads();                               // pass A fully done; drain once

  // ================= PASS B: recompute + stream fp32 attn =================
  float* const arow = attn + ((size_t)bh * S_LEN + q0 + w*16 + cl) * S_LEN + g*4;

  for (int i = 0; i < 6; ++i) STAGE_K(i);
  for (int c = 0; c < 64; ++c) {
    STAGE_K(c + 6);
    if (w < 4) {                                  // waves 4-7: ZERO vmcnt waits
      if (c < 6) asm volatile("s_waitcnt vmcnt(6)"  ::: "memory");
      else       asm volatile("s_waitcnt vmcnt(18)" ::: "memory");  // 6-chunk store slack
    }
    __builtin_amdgcn_s_barrier();
    __builtin_amdgcn_sched_barrier(0);
    AS3 const char* kb = KB + (c & 7) * 4096;
    #pragma unroll
    for (int s = 0; s < 2; ++s) {
      const bf16x8 k0 = *(const AS3 bf16x8*)(kb + s*2048 + koff0);
      const bf16x8 k1 = *(const AS3 bf16x8*)(kb + s*2048 + koff1);
      f32x4 acc = {0.f, 0.f, 0.f, 0.f};
      acc = mfma16(k0, qf0, acc);
      acc = mfma16(k1, qf1, acc);
      f32x4 p;
      p[0] = __builtin_exp2f(acc[0] * SC2) * inv;
      p[1] = __builtin_exp2f(acc[1] * SC2) * inv;
      p[2] = __builtin_exp2f(acc[2] * SC2) * inv;
      p[3] = __builtin_exp2f(acc[3] * SC2) * inv;
      *reinterpret_cast<f32x4*>(arow + c*32 + s*16) = p;   // 16 rows x 64B / instr
    }
  }
  #undef STAGE_KV
  #undef STAGE_K
}

// ---------------------------------------------------------------------------
extern "C" void kernel_launch(void* const* d_in, const int* in_sizes, int n_in,
                              void* d_out, int out_size, void* d_ws, size_t ws_size,
                              hipStream_t stream)
{
  const float* q_in = (const float*)d_in[0];
  const float* k_in = (const float*)d_in[1];
  const float* v_in = (const float*)d_in[2];
  const float* Wq   = (const float*)d_in[3];
  const float* bq   = (const float*)d_in[4];
  const float* Wk   = (const float*)d_in[5];
  const float* bk   = (const float*)d_in[6];
  const float* Wv   = (const float*)d_in[7];
  const float* bv   = (const float*)d_in[8];
  const float* Wo   = (const float*)d_in[9];
  const float* bo   = (const float*)d_in[10];

  unsigned short* qbf  = (unsigned short*)d_ws;
  unsigned short* kbf  = qbf  + (size_t)MTOK*DM;
  unsigned short* vbf  = kbf  + (size_t)MTOK*DM;
  unsigned short* wqbf = vbf  + (size_t)MTOK*DM;
  unsigned short* wkbf = wqbf + (size_t)DM*DM;
  unsigned short* wvbf = wkbf + (size_t)DM*DM;
  unsigned short* wobf = wvbf + (size_t)DM*DM;
  unsigned short* Qhp  = wobf + (size_t)DM*DM;    // [b,h,s,d]
  unsigned short* Khp  = Qhp  + (size_t)MTOK*DM;  // [b,h,s,d]
  unsigned short* Vtp  = Khp  + (size_t)MTOK*DM;  // [b,h,d,s]
  unsigned short* ctx  = Vtp  + (size_t)MTOK*DM;  // [b*s, h*d]

  float* out0 = (float*)d_out;
  float* attn = out0 + (size_t)MTOK*DM;

  CvtArgs ca;
  ca.src[0] = q_in; ca.dst[0] = qbf;  ca.n[0] = MTOK*DM;
  ca.src[1] = k_in; ca.dst[1] = kbf;  ca.n[1] = MTOK*DM;
  ca.src[2] = v_in; ca.dst[2] = vbf;  ca.n[2] = MTOK*DM;
  ca.src[3] = Wq;   ca.dst[3] = wqbf; ca.n[3] = DM*DM;
  ca.src[4] = Wk;   ca.dst[4] = wkbf; ca.n[4] = DM*DM;
  ca.src[5] = Wv;   ca.dst[5] = wvbf; ca.n[5] = DM*DM;
  ca.src[6] = Wo;   ca.dst[6] = wobf; ca.n[6] = DM*DM;
  cvt_f32_bf16<<<dim3(512, 7), 256, 0, stream>>>(ca);

  gemm_bt<0><<<dim3(8, 32), 256, 0, stream>>>(qbf, wqbf, bq, Qhp, MTOK, DM, DM);
  gemm_bt<0><<<dim3(8, 32), 256, 0, stream>>>(kbf, wkbf, bk, Khp, MTOK, DM, DM);
  gemm_bt<1><<<dim3(8, 32), 256, 0, stream>>>(vbf, wvbf, bv, Vtp, MTOK, DM, DM);

  attn_fused7<<<dim3(512), 512, 0, stream>>>(Qhp, Khp, Vtp, attn, ctx);

  gemm_bt<2><<<dim3(8, 32), 256, 0, stream>>>(ctx, wobf, bo, (void*)out0, MTOK, DM, DM);
}

// Round 8
// 341.371 us; speedup vs baseline: 1.6275x; 1.0040x over previous
//
#include <hip/hip_runtime.h>
#include <hip/hip_bf16.h>
#include <stdint.h>

#define S_LEN 2048
#define NB 2
#define NH 16
#define DM 1024
#define KDIM 64
#define MTOK (NB*S_LEN)   // 4096 tokens

typedef __attribute__((ext_vector_type(8))) short bf16x8;
typedef __attribute__((ext_vector_type(4))) float f32x4;
typedef __attribute__((ext_vector_type(4))) unsigned short u16x4;
typedef __attribute__((ext_vector_type(8))) unsigned short u16x8;

#define AS1 __attribute__((address_space(1)))
#define AS3 __attribute__((address_space(3)))

__device__ __forceinline__ unsigned short f2bf(float f) {
  unsigned int u = __builtin_bit_cast(unsigned int, f);
  return (unsigned short)((u + 0x7fffu + ((u >> 16) & 1u)) >> 16);   // RNE
}
__device__ __forceinline__ f32x4 mfma16(bf16x8 a, bf16x8 b, f32x4 c) {
  return __builtin_amdgcn_mfma_f32_16x16x32_bf16(a, b, c, 0, 0, 0);
}

// ---------------------------------------------------------------------------
// fp32 -> bf16 convert, 7 segments (q,k,v inputs + Wq,Wk,Wv,Wo)
// ---------------------------------------------------------------------------
struct CvtArgs {
  const float* src[7];
  unsigned short* dst[7];
  int n[7];
};

__global__ __launch_bounds__(256) void cvt_f32_bf16(CvtArgs a) {
  const int seg = blockIdx.y;
  const float* __restrict__ s = a.src[seg];
  unsigned short* __restrict__ d = a.dst[seg];
  const int n4 = a.n[seg] >> 2;
  const int stride = gridDim.x * blockDim.x;
  for (int i = blockIdx.x * blockDim.x + threadIdx.x; i < n4; i += stride) {
    const float4 v = reinterpret_cast<const float4*>(s)[i];
    u16x4 o;
    o[0] = f2bf(v.x); o[1] = f2bf(v.y); o[2] = f2bf(v.z); o[3] = f2bf(v.w);
    reinterpret_cast<u16x4*>(d)[i] = o;
  }
}

// ---------------------------------------------------------------------------
// GEMM: C[m,n] = sum_k A[m,k]*Bw[n,k] + bias[n]   (A,Bw bf16 row-major, K-contig)
// 128x128 tile, BK=32, 4 waves (2x2), global_load_lds width-16 staging.
// MODE 0: bf16 out scattered to [b,h,s,d]   (Q, K) — 32B segments
// MODE 1: bf16 out to [b,h,d,s] via LDS-transposed epilogue (V)
// MODE 2: fp32 out row-major [M,N]          (final projection)
// ---------------------------------------------------------------------------
template<int MODE>
__global__ __launch_bounds__(256, 2)
void gemm_bt(const unsigned short* __restrict__ A,
             const unsigned short* __restrict__ Bw,
             const float* __restrict__ bias,
             void* __restrict__ dst,
             const int M, const int N, const int K)
{
  __shared__ __align__(16) unsigned short As[128*32];
  __shared__ __align__(16) unsigned short Bs[128*32];
  const int t = threadIdx.x;
  const int w = t >> 6, l = t & 63;
  const int g = l >> 4, cl = l & 15;
  const int m0 = blockIdx.y * 128;
  const int n0 = blockIdx.x * 128;

  const unsigned short* Ag = A + (size_t)(m0 + (t >> 2)) * K + (t & 3) * 8;
  const unsigned short* Bg = Bw + (size_t)(n0 + (t >> 2)) * K + (t & 3) * 8;
  AS3 unsigned short* lA = (AS3 unsigned short*)As + w * 512;
  AS3 unsigned short* lB = (AS3 unsigned short*)Bs + w * 512;

  const int wm = (w >> 1) * 64, wn = (w & 1) * 64;

  f32x4 acc[4][4];
  for (int i = 0; i < 4; ++i) for (int j = 0; j < 4; ++j) acc[i][j] = 0.f;

  for (int kt = 0; kt < K; kt += 32) {
    __builtin_amdgcn_global_load_lds((const AS1 void*)(Ag + kt),                   (AS3 void*)lA,          16, 0, 0);
    __builtin_amdgcn_global_load_lds((const AS1 void*)(Ag + kt + (size_t)64 * K),  (AS3 void*)(lA + 2048), 16, 0, 0);
    __builtin_amdgcn_global_load_lds((const AS1 void*)(Bg + kt),                   (AS3 void*)lB,          16, 0, 0);
    __builtin_amdgcn_global_load_lds((const AS1 void*)(Bg + kt + (size_t)64 * K),  (AS3 void*)(lB + 2048), 16, 0, 0);
    __syncthreads();
    bf16x8 af[4], bfv[4];
    for (int i = 0; i < 4; ++i)
      af[i] = *reinterpret_cast<const bf16x8*>(&As[(wm + 16*i + cl) * 32 + g*8]);
    for (int j = 0; j < 4; ++j)
      bfv[j] = *reinterpret_cast<const bf16x8*>(&Bs[(wn + 16*j + cl) * 32 + g*8]);
    for (int i = 0; i < 4; ++i)
      for (int j = 0; j < 4; ++j)
        acc[i][j] = mfma16(af[i], bfv[j], acc[i][j]);
    __syncthreads();
  }

  if constexpr (MODE == 1) {
    // LDS-transposed epilogue: Cs[n][m] (bf16), 8B-unit XOR swizzle per row.
    __shared__ __align__(16) unsigned short Cs[128*128];   // 32 KB
    #pragma unroll
    for (int i = 0; i < 4; ++i) {
      #pragma unroll
      for (int j = 0; j < 4; ++j) {
        const int n = wn + 16*j + cl;
        const float bn = bias[n0 + n];
        const int u = (wm >> 2) + 4*i + g;       // 8B unit (= m/4) within row
        const int us = u ^ (n & 31);             // bank-conflict-free swizzle
        u16x4 o;
        #pragma unroll
        for (int r = 0; r < 4; ++r) o[r] = f2bf(acc[i][j][r] + bn);
        *reinterpret_cast<u16x4*>(&Cs[n*128 + us*4]) = o;
      }
    }
    __syncthreads();
    // readout: thread t owns row n = t>>1, m-half mh = (t&1)*64 -> 128B contig
    {
      const int n = t >> 1, mh = (t & 1) * 64;
      const int ncol = n0 + n;
      const int h = ncol >> 6, d = ncol & (KDIM-1);
      const int b = m0 >> 11, s0 = m0 & (S_LEN-1);
      unsigned short* drow = (unsigned short*)dst
          + ((size_t)(b*NH + h)*KDIM + d)*S_LEN + s0 + mh;
      #pragma unroll
      for (int mm = 0; mm < 4; ++mm) {           // 16 m-values per iter (32B)
        u16x4 v[4];
        #pragma unroll
        for (int k = 0; k < 4; ++k) {
          const int us = ((mh >> 2) + mm*4 + k) ^ (n & 31);
          v[k] = *reinterpret_cast<const u16x4*>(&Cs[n*128 + us*4]);
        }
        u16x8 w01, w23;
        #pragma unroll
        for (int e = 0; e < 4; ++e) {
          w01[e] = v[0][e]; w01[4+e] = v[1][e];
          w23[e] = v[2][e]; w23[4+e] = v[3][e];
        }
        *reinterpret_cast<u16x8*>(drow + mm*16)     = w01;
        *reinterpret_cast<u16x8*>(drow + mm*16 + 8) = w23;
      }
    }
  } else {
    for (int i = 0; i < 4; ++i) for (int j = 0; j < 4; ++j) {
      const int ncol = n0 + wn + 16*j + cl;
      const float bn = bias[ncol];
      for (int r = 0; r < 4; ++r) {
        const int m = m0 + wm + 16*i + g*4 + r;
        const float v = acc[i][j][r] + bn;
        if (MODE == 0) {
          const int b = m >> 11, s = m & (S_LEN-1);
          const int h = ncol >> 6, d = ncol & (KDIM-1);
          ((unsigned short*)dst)[((size_t)(b*NH + h)*S_LEN + s)*KDIM + d] = f2bf(v);
        } else {
          ((float*)dst)[(size_t)m * N + ncol] = v;
        }
      }
    }
  }
}

// ---------------------------------------------------------------------------
// Fused attention v7 (unchanged from R7): block = 128 q-rows x all 2048 kv;
// 8 waves x 16 rows. K/V staged in LDS: 8 buffers, stage 6 ahead, counted
// vmcnt so stores are never drained by a load-wait. Pass A: sums+PV (no
// stores). Pass B: recompute from LDS K, stream fp32 attn.
// ---------------------------------------------------------------------------
__global__ __launch_bounds__(512, 4)
void attn_fused7(const unsigned short* __restrict__ Qh,
                 const unsigned short* __restrict__ Kh,
                 const unsigned short* __restrict__ Vt,
                 float* __restrict__ attn,
                 unsigned short* __restrict__ ctx)
{
  __shared__ __align__(16) char smem[75776];
  AS3 char* const KB = (AS3 char*)smem;
  AS3 char* const VB = (AS3 char*)smem + 32768;

  const int id  = blockIdx.x;                 // 512 blocks = 8 XCD x 64
  const int swz = (id & 7) * 64 + (id >> 3);  // bijective XCD swizzle
  const int bh  = swz >> 4;                   // head 0..31
  const int q0  = (swz & 15) * 128;           // 128-row q tile

  const int t = threadIdx.x, w = t >> 6, l = t & 63;
  const int g = l >> 4, cl = l & 15;
  AS3 char* const PBw = (AS3 char*)smem + 65536 + w * 1280;
  const int b = bh >> 4, h = bh & 15;

  const unsigned short* Qb = Qh + ((size_t)bh * S_LEN + q0 + w*16 + cl) * KDIM;
  const bf16x8 qf0 = *reinterpret_cast<const bf16x8*>(Qb + g*8);
  const bf16x8 qf1 = *reinterpret_cast<const bf16x8*>(Qb + 32 + g*8);

  const int rs = (w & 3)*8 + (l >> 3), js = l & 7;
  const unsigned short* pK = Kh + (size_t)bh*S_LEN*KDIM + (size_t)rs*KDIM
                                + (size_t)((js ^ (rs & 7)) * 8);
  const int dsv = (w & 3)*16 + (l >> 2), jv = l & 3;
  const int kst = (dsv & 3) ^ ((dsv >> 2) & 3);
  const unsigned short* pV = Vt + (size_t)bh*KDIM*S_LEN + (size_t)dsv*S_LEN
                                + (size_t)((jv ^ kst) * 8);

  const unsigned kvkey = (unsigned)((cl & 3) ^ ((cl >> 2) & 3));
  const unsigned koff0 = (unsigned)(cl*128 + ((g ^ (cl & 7)) << 4));
  const unsigned koff1 = (unsigned)(cl*128 + (((g + 4) ^ (cl & 7)) << 4));
  const float SC2 = 0.125f * 1.44269504f;     // 1/sqrt(64) * log2(e)

  #define STAGE_KV(ch) do { int _b = (ch) & 7;                                              \
    if (w < 4) __builtin_amdgcn_global_load_lds((const AS1 void*)(pK + (size_t)(ch)*2048),  \
                   (AS3 void*)(KB + _b*4096 + (w&3)*1024), 16, 0, 0);                       \
    else       __builtin_amdgcn_global_load_lds((const AS1 void*)(pV + (size_t)(ch)*32),    \
                   (AS3 void*)(VB + _b*4096 + (w&3)*1024), 16, 0, 0); } while (0)
  #define STAGE_K(ch) do { int _b = (ch) & 7;                                               \
    if (w < 4) __builtin_amdgcn_global_load_lds((const AS1 void*)(pK + (size_t)(ch)*2048),  \
                   (AS3 void*)(KB + _b*4096 + (w&3)*1024), 16, 0, 0); } while (0)

  // ================= PASS A: sums + PV (no global stores) =================
  float sa0 = 0.f, sa1 = 0.f, sa2 = 0.f, sa3 = 0.f;
  f32x4 accP[4];
  #pragma unroll
  for (int dt = 0; dt < 4; ++dt) accP[dt] = 0.f;

  for (int i = 0; i < 6; ++i) STAGE_KV(i);
  for (int c = 0; c < 64; ++c) {
    STAGE_KV(c + 6);
    asm volatile("s_waitcnt vmcnt(6)" ::: "memory");
    __builtin_amdgcn_s_barrier();
    __builtin_amdgcn_sched_barrier(0);
    AS3 const char* kb = KB + (c & 7) * 4096;
    AS3 const char* vb = VB + (c & 7) * 4096;
    #pragma unroll
    for (int s = 0; s < 2; ++s) {
      const bf16x8 k0 = *(const AS3 bf16x8*)(kb + s*2048 + koff0);
      const bf16x8 k1 = *(const AS3 bf16x8*)(kb + s*2048 + koff1);
      f32x4 acc = {0.f, 0.f, 0.f, 0.f};
      acc = mfma16(k0, qf0, acc);
      acc = mfma16(k1, qf1, acc);
      const float p0 = __builtin_exp2f(acc[0] * SC2);
      const float p1 = __builtin_exp2f(acc[1] * SC2);
      const float p2 = __builtin_exp2f(acc[2] * SC2);
      const float p3 = __builtin_exp2f(acc[3] * SC2);
      sa0 += p0; sa1 += p1; sa2 += p2; sa3 += p3;
      u16x4 pb;
      pb[0] = f2bf(p0); pb[1] = f2bf(p1); pb[2] = f2bf(p2); pb[3] = f2bf(p3);
      *(AS3 u16x4*)(PBw + cl*80 + s*32 + g*8) = pb;
    }
    const bf16x8 ap = *(const AS3 bf16x8*)(PBw + cl*80 + g*16);
    #pragma unroll
    for (int dt = 0; dt < 4; ++dt) {
      const bf16x8 bv = *(const AS3 bf16x8*)(vb + (dt*16 + cl)*64 + ((g ^ kvkey) << 4));
      accP[dt] = mfma16(ap, bv, accP[dt]);
    }
  }

  float ssum = (sa0 + sa1) + (sa2 + sa3);
  ssum += __shfl_xor(ssum, 16, 64);
  ssum += __shfl_xor(ssum, 32, 64);
  const float inv = 1.0f / ssum;

  #pragma unroll
  for (int r = 0; r < 4; ++r) {
    const float invq = __shfl(inv, g*4 + r, 64);
    const size_t row = (size_t)(b * S_LEN + q0 + w*16 + g*4 + r);
    #pragma unroll
    for (int dt = 0; dt < 4; ++dt)
      ctx[row * DM + h * KDIM + dt*16 + cl] = f2bf(accP[dt][r] * invq);
  }

  __syncthreads();

  // ================= PASS B: recompute + stream fp32 attn =================
  float* const arow = attn + ((size_t)bh * S_LEN + q0 + w*16 + cl) * S_LEN + g*4;

  for (int i = 0; i < 6; ++i) STAGE_K(i);
  for (int c = 0; c < 64; ++c) {
    STAGE_K(c + 6);
    if (w < 4) {
      if (c < 6) asm volatile("s_waitcnt vmcnt(6)"  ::: "memory");
      else       asm volatile("s_waitcnt vmcnt(18)" ::: "memory");
    }
    __builtin_amdgcn_s_barrier();
    __builtin_amdgcn_sched_barrier(0);
    AS3 const char* kb = KB + (c & 7) * 4096;
    #pragma unroll
    for (int s = 0; s < 2; ++s) {
      const bf16x8 k0 = *(const AS3 bf16x8*)(kb + s*2048 + koff0);
      const bf16x8 k1 = *(const AS3 bf16x8*)(kb + s*2048 + koff1);
      f32x4 acc = {0.f, 0.f, 0.f, 0.f};
      acc = mfma16(k0, qf0, acc);
      acc = mfma16(k1, qf1, acc);
      f32x4 p;
      p[0] = __builtin_exp2f(acc[0] * SC2) * inv;
      p[1] = __builtin_exp2f(acc[1] * SC2) * inv;
      p[2] = __builtin_exp2f(acc[2] * SC2) * inv;
      p[3] = __builtin_exp2f(acc[3] * SC2) * inv;
      *reinterpret_cast<f32x4*>(arow + c*32 + s*16) = p;
    }
  }
  #undef STAGE_KV
  #undef STAGE_K
}

// ---------------------------------------------------------------------------
extern "C" void kernel_launch(void* const* d_in, const int* in_sizes, int n_in,
                              void* d_out, int out_size, void* d_ws, size_t ws_size,
                              hipStream_t stream)
{
  const float* q_in = (const float*)d_in[0];
  const float* k_in = (const float*)d_in[1];
  const float* v_in = (const float*)d_in[2];
  const float* Wq   = (const float*)d_in[3];
  const float* bq   = (const float*)d_in[4];
  const float* Wk   = (const float*)d_in[5];
  const float* bk   = (const float*)d_in[6];
  const float* Wv   = (const float*)d_in[7];
  const float* bv   = (const float*)d_in[8];
  const float* Wo   = (const float*)d_in[9];
  const float* bo   = (const float*)d_in[10];

  unsigned short* qbf  = (unsigned short*)d_ws;
  unsigned short* kbf  = qbf  + (size_t)MTOK*DM;
  unsigned short* vbf  = kbf  + (size_t)MTOK*DM;
  unsigned short* wqbf = vbf  + (size_t)MTOK*DM;
  unsigned short* wkbf = wqbf + (size_t)DM*DM;
  unsigned short* wvbf = wkbf + (size_t)DM*DM;
  unsigned short* wobf = wvbf + (size_t)DM*DM;
  unsigned short* Qhp  = wobf + (size_t)DM*DM;    // [b,h,s,d]
  unsigned short* Khp  = Qhp  + (size_t)MTOK*DM;  // [b,h,s,d]
  unsigned short* Vtp  = Khp  + (size_t)MTOK*DM;  // [b,h,d,s]
  unsigned short* ctx  = Vtp  + (size_t)MTOK*DM;  // [b*s, h*d]

  float* out0 = (float*)d_out;
  float* attn = out0 + (size_t)MTOK*DM;

  CvtArgs ca;
  ca.src[0] = q_in; ca.dst[0] = qbf;  ca.n[0] = MTOK*DM;
  ca.src[1] = k_in; ca.dst[1] = kbf;  ca.n[1] = MTOK*DM;
  ca.src[2] = v_in; ca.dst[2] = vbf;  ca.n[2] = MTOK*DM;
  ca.src[3] = Wq;   ca.dst[3] = wqbf; ca.n[3] = DM*DM;
  ca.src[4] = Wk;   ca.dst[4] = wkbf; ca.n[4] = DM*DM;
  ca.src[5] = Wv;   ca.dst[5] = wvbf; ca.n[5] = DM*DM;
  ca.src[6] = Wo;   ca.dst[6] = wobf; ca.n[6] = DM*DM;
  cvt_f32_bf16<<<dim3(512, 7), 256, 0, stream>>>(ca);

  gemm_bt<0><<<dim3(8, 32), 256, 0, stream>>>(qbf, wqbf, bq, Qhp, MTOK, DM, DM);
  gemm_bt<0><<<dim3(8, 32), 256, 0, stream>>>(kbf, wkbf, bk, Khp, MTOK, DM, DM);
  gemm_bt<1><<<dim3(8, 32), 256, 0, stream>>>(vbf, wvbf, bv, Vtp, MTOK, DM, DM);

  attn_fused7<<<dim3(512), 512, 0, stream>>>(Qhp, Khp, Vtp, attn, ctx);

  gemm_bt<2><<<dim3(8, 32), 256, 0, stream>>>(ctx, wobf, bo, (void*)out0, MTOK, DM, DM);
}

// Round 9
// 298.903 us; speedup vs baseline: 1.8587x; 1.1421x over previous
//
#include <hip/hip_runtime.h>
#include <hip/hip_bf16.h>
#include <stdint.h>

#define S_LEN 2048
#define NB 2
#define NH 16
#define DM 1024
#define KDIM 64
#define MTOK (NB*S_LEN)   // 4096 tokens

typedef __attribute__((ext_vector_type(8))) short bf16x8;
typedef __attribute__((ext_vector_type(4))) float f32x4;
typedef __attribute__((ext_vector_type(4))) unsigned short u16x4;
typedef __attribute__((ext_vector_type(8))) unsigned short u16x8;

#define AS1 __attribute__((address_space(1)))
#define AS3 __attribute__((address_space(3)))

__device__ __forceinline__ unsigned short f2bf(float f) {
  unsigned int u = __builtin_bit_cast(unsigned int, f);
  return (unsigned short)((u + 0x7fffu + ((u >> 16) & 1u)) >> 16);   // RNE
}
__device__ __forceinline__ f32x4 mfma16(bf16x8 a, bf16x8 b, f32x4 c) {
  return __builtin_amdgcn_mfma_f32_16x16x32_bf16(a, b, c, 0, 0, 0);
}

// ---------------------------------------------------------------------------
// fp32 -> bf16 convert, 7 segments (q,k,v inputs + Wq,Wk,Wv,Wo)
// ---------------------------------------------------------------------------
struct CvtArgs {
  const float* src[7];
  unsigned short* dst[7];
  int n[7];
};

__global__ __launch_bounds__(256) void cvt_f32_bf16(CvtArgs a) {
  const int seg = blockIdx.y;
  const float* __restrict__ s = a.src[seg];
  unsigned short* __restrict__ d = a.dst[seg];
  const int n4 = a.n[seg] >> 2;
  const int stride = gridDim.x * blockDim.x;
  for (int i = blockIdx.x * blockDim.x + threadIdx.x; i < n4; i += stride) {
    const float4 v = reinterpret_cast<const float4*>(s)[i];
    u16x4 o;
    o[0] = f2bf(v.x); o[1] = f2bf(v.y); o[2] = f2bf(v.z); o[3] = f2bf(v.w);
    reinterpret_cast<u16x4*>(d)[i] = o;
  }
}

// ---------------------------------------------------------------------------
// Pipelined GEMM: C[m,n] = sum_k A[m,k]*W[n,k] + bias[n], M=4096 N=K=1024.
// 128x128 tile, BK=32, double-buffered LDS staging with counted vmcnt
// (never drained mid-loop) + raw s_barrier — R7-proven pipeline.
// Batched over blockIdx.z (Q/K/V projections co-resident: 3 blocks/CU).
// mode 0: bf16 -> [b,h,s,d]; mode 1: bf16 -> [b,h,d,s] via LDS transpose;
// mode 2: fp32 row-major.
// ---------------------------------------------------------------------------
struct GemmArgs {
  const unsigned short* A[3];
  const unsigned short* W[3];
  const float* bias[3];
  void* dst[3];
  int mode[3];
};

__global__ __launch_bounds__(256, 2)
void gemm_pipe(GemmArgs ga)
{
  __shared__ __align__(16) char smem[32768];   // 2 x (A 8K + B 8K); Cs union

  const int z = blockIdx.z;
  const unsigned short* __restrict__ A  = ga.A[z];
  const unsigned short* __restrict__ Bw = ga.W[z];
  const float* __restrict__ bias = ga.bias[z];
  void* __restrict__ dst = ga.dst[z];
  const int mode = ga.mode[z];

  const int t = threadIdx.x;
  const int w = t >> 6, l = t & 63;
  const int g = l >> 4, cl = l & 15;
  const int m0 = blockIdx.y * 128;
  const int n0 = blockIdx.x * 128;

  const unsigned short* Ag = A  + (size_t)(m0 + (t >> 2)) * DM + (t & 3) * 8;
  const unsigned short* Bg = Bw + (size_t)(n0 + (t >> 2)) * DM + (t & 3) * 8;

  const int wm = (w >> 1) * 64, wn = (w & 1) * 64;

  f32x4 acc[4][4];
  #pragma unroll
  for (int i = 0; i < 4; ++i)
    #pragma unroll
    for (int j = 0; j < 4; ++j) acc[i][j] = 0.f;

  #define STAGE(step) do {                                                          \
    AS3 char* _buf = (AS3 char*)smem + ((step) & 1) * 16384;                         \
    __builtin_amdgcn_global_load_lds((const AS1 void*)(Ag + (step)*32),              \
                                     (AS3 void*)(_buf + w*1024),          16, 0, 0); \
    __builtin_amdgcn_global_load_lds((const AS1 void*)(Ag + (step)*32 + 64*DM),      \
                                     (AS3 void*)(_buf + 4096 + w*1024),   16, 0, 0); \
    __builtin_amdgcn_global_load_lds((const AS1 void*)(Bg + (step)*32),              \
                                     (AS3 void*)(_buf + 8192 + w*1024),   16, 0, 0); \
    __builtin_amdgcn_global_load_lds((const AS1 void*)(Bg + (step)*32 + 64*DM),      \
                                     (AS3 void*)(_buf + 12288 + w*1024),  16, 0, 0); \
  } while (0)

  STAGE(0);
  for (int s = 0; s < 32; ++s) {
    if (s < 31) {
      STAGE(s + 1);
      asm volatile("s_waitcnt vmcnt(4)" ::: "memory");   // tile-s loads landed
    } else {
      asm volatile("s_waitcnt vmcnt(0)" ::: "memory");
    }
    __builtin_amdgcn_s_barrier();
    __builtin_amdgcn_sched_barrier(0);

    const AS3 unsigned short* bufA =
        (const AS3 unsigned short*)((AS3 char*)smem + (s & 1) * 16384);
    const AS3 unsigned short* bufB = bufA + 4096;
    bf16x8 af[4], bfv[4];
    #pragma unroll
    for (int i = 0; i < 4; ++i)
      af[i] = *(const AS3 bf16x8*)(bufA + (wm + 16*i + cl) * 32 + g*8);
    #pragma unroll
    for (int j = 0; j < 4; ++j)
      bfv[j] = *(const AS3 bf16x8*)(bufB + (wn + 16*j + cl) * 32 + g*8);
    #pragma unroll
    for (int i = 0; i < 4; ++i)
      #pragma unroll
      for (int j = 0; j < 4; ++j)
        acc[i][j] = mfma16(af[i], bfv[j], acc[i][j]);

    __builtin_amdgcn_sched_barrier(0);
    __builtin_amdgcn_s_barrier();              // all reads of buf[s&1] done
  }
  #undef STAGE

  if (mode == 1) {
    // LDS-transposed epilogue (unions smem): Cs[n][m] bf16, 8B-unit XOR swizzle.
    unsigned short* Cs = (unsigned short*)smem;
    __syncthreads();
    #pragma unroll
    for (int i = 0; i < 4; ++i) {
      #pragma unroll
      for (int j = 0; j < 4; ++j) {
        const int n = wn + 16*j + cl;
        const float bn = bias[n0 + n];
        const int u = (wm >> 2) + 4*i + g;
        const int us = u ^ (n & 31);
        u16x4 o;
        #pragma unroll
        for (int r = 0; r < 4; ++r) o[r] = f2bf(acc[i][j][r] + bn);
        *reinterpret_cast<u16x4*>(&Cs[n*128 + us*4]) = o;
      }
    }
    __syncthreads();
    {
      const int n = t >> 1, mh = (t & 1) * 64;
      const int ncol = n0 + n;
      const int h = ncol >> 6, d = ncol & (KDIM-1);
      const int b = m0 >> 11, s0 = m0 & (S_LEN-1);
      unsigned short* drow = (unsigned short*)dst
          + ((size_t)(b*NH + h)*KDIM + d)*S_LEN + s0 + mh;
      #pragma unroll
      for (int mm = 0; mm < 4; ++mm) {
        u16x4 v[4];
        #pragma unroll
        for (int k = 0; k < 4; ++k) {
          const int us = ((mh >> 2) + mm*4 + k) ^ (n & 31);
          v[k] = *reinterpret_cast<const u16x4*>(&Cs[n*128 + us*4]);
        }
        u16x8 w01, w23;
        #pragma unroll
        for (int e = 0; e < 4; ++e) {
          w01[e] = v[0][e]; w01[4+e] = v[1][e];
          w23[e] = v[2][e]; w23[4+e] = v[3][e];
        }
        *reinterpret_cast<u16x8*>(drow + mm*16)     = w01;
        *reinterpret_cast<u16x8*>(drow + mm*16 + 8) = w23;
      }
    }
  } else {
    #pragma unroll
    for (int i = 0; i < 4; ++i)
      #pragma unroll
      for (int j = 0; j < 4; ++j) {
        const int ncol = n0 + wn + 16*j + cl;
        const float bn = bias[ncol];
        #pragma unroll
        for (int r = 0; r < 4; ++r) {
          const int m = m0 + wm + 16*i + g*4 + r;
          const float v = acc[i][j][r] + bn;
          if (mode == 0) {
            const int b = m >> 11, sR = m & (S_LEN-1);
            const int h = ncol >> 6, d = ncol & (KDIM-1);
            ((unsigned short*)dst)[((size_t)(b*NH + h)*S_LEN + sR)*KDIM + d] = f2bf(v);
          } else {
            ((float*)dst)[(size_t)m * DM + ncol] = v;
          }
        }
      }
  }
}

// ---------------------------------------------------------------------------
// Fused attention v7 (unchanged, R7-verified): block = 128 q-rows x 2048 kv;
// 8 waves x 16 rows. K/V staged via 8 LDS buffers, stage 6 ahead, counted
// vmcnt so stores are never drained by a load-wait. Pass A: sums+PV (no
// stores). Pass B: recompute from LDS K, stream fp32 attn.
// ---------------------------------------------------------------------------
__global__ __launch_bounds__(512, 4)
void attn_fused7(const unsigned short* __restrict__ Qh,
                 const unsigned short* __restrict__ Kh,
                 const unsigned short* __restrict__ Vt,
                 float* __restrict__ attn,
                 unsigned short* __restrict__ ctx)
{
  __shared__ __align__(16) char smem[75776];
  AS3 char* const KB = (AS3 char*)smem;
  AS3 char* const VB = (AS3 char*)smem + 32768;

  const int id  = blockIdx.x;                 // 512 blocks = 8 XCD x 64
  const int swz = (id & 7) * 64 + (id >> 3);  // bijective XCD swizzle
  const int bh  = swz >> 4;                   // head 0..31
  const int q0  = (swz & 15) * 128;           // 128-row q tile

  const int t = threadIdx.x, w = t >> 6, l = t & 63;
  const int g = l >> 4, cl = l & 15;
  AS3 char* const PBw = (AS3 char*)smem + 65536 + w * 1280;
  const int b = bh >> 4, h = bh & 15;

  const unsigned short* Qb = Qh + ((size_t)bh * S_LEN + q0 + w*16 + cl) * KDIM;
  const bf16x8 qf0 = *reinterpret_cast<const bf16x8*>(Qb + g*8);
  const bf16x8 qf1 = *reinterpret_cast<const bf16x8*>(Qb + 32 + g*8);

  const int rs = (w & 3)*8 + (l >> 3), js = l & 7;
  const unsigned short* pK = Kh + (size_t)bh*S_LEN*KDIM + (size_t)rs*KDIM
                                + (size_t)((js ^ (rs & 7)) * 8);
  const int dsv = (w & 3)*16 + (l >> 2), jv = l & 3;
  const int kst = (dsv & 3) ^ ((dsv >> 2) & 3);
  const unsigned short* pV = Vt + (size_t)bh*KDIM*S_LEN + (size_t)dsv*S_LEN
                                + (size_t)((jv ^ kst) * 8);

  const unsigned kvkey = (unsigned)((cl & 3) ^ ((cl >> 2) & 3));
  const unsigned koff0 = (unsigned)(cl*128 + ((g ^ (cl & 7)) << 4));
  const unsigned koff1 = (unsigned)(cl*128 + (((g + 4) ^ (cl & 7)) << 4));
  const float SC2 = 0.125f * 1.44269504f;     // 1/sqrt(64) * log2(e)

  #define STAGE_KV(ch) do { int _b = (ch) & 7;                                              \
    if (w < 4) __builtin_amdgcn_global_load_lds((const AS1 void*)(pK + (size_t)(ch)*2048),  \
                   (AS3 void*)(KB + _b*4096 + (w&3)*1024), 16, 0, 0);                       \
    else       __builtin_amdgcn_global_load_lds((const AS1 void*)(pV + (size_t)(ch)*32),    \
                   (AS3 void*)(VB + _b*4096 + (w&3)*1024), 16, 0, 0); } while (0)
  #define STAGE_K(ch) do { int _b = (ch) & 7;                                               \
    if (w < 4) __builtin_amdgcn_global_load_lds((const AS1 void*)(pK + (size_t)(ch)*2048),  \
                   (AS3 void*)(KB + _b*4096 + (w&3)*1024), 16, 0, 0); } while (0)

  // ================= PASS A: sums + PV (no global stores) =================
  float sa0 = 0.f, sa1 = 0.f, sa2 = 0.f, sa3 = 0.f;
  f32x4 accP[4];
  #pragma unroll
  for (int dt = 0; dt < 4; ++dt) accP[dt] = 0.f;

  for (int i = 0; i < 6; ++i) STAGE_KV(i);
  for (int c = 0; c < 64; ++c) {
    STAGE_KV(c + 6);
    asm volatile("s_waitcnt vmcnt(6)" ::: "memory");
    __builtin_amdgcn_s_barrier();
    __builtin_amdgcn_sched_barrier(0);
    AS3 const char* kb = KB + (c & 7) * 4096;
    AS3 const char* vb = VB + (c & 7) * 4096;
    #pragma unroll
    for (int s = 0; s < 2; ++s) {
      const bf16x8 k0 = *(const AS3 bf16x8*)(kb + s*2048 + koff0);
      const bf16x8 k1 = *(const AS3 bf16x8*)(kb + s*2048 + koff1);
      f32x4 acc = {0.f, 0.f, 0.f, 0.f};
      acc = mfma16(k0, qf0, acc);
      acc = mfma16(k1, qf1, acc);
      const float p0 = __builtin_exp2f(acc[0] * SC2);
      const float p1 = __builtin_exp2f(acc[1] * SC2);
      const float p2 = __builtin_exp2f(acc[2] * SC2);
      const float p3 = __builtin_exp2f(acc[3] * SC2);
      sa0 += p0; sa1 += p1; sa2 += p2; sa3 += p3;
      u16x4 pb;
      pb[0] = f2bf(p0); pb[1] = f2bf(p1); pb[2] = f2bf(p2); pb[3] = f2bf(p3);
      *(AS3 u16x4*)(PBw + cl*80 + s*32 + g*8) = pb;
    }
    const bf16x8 ap = *(const AS3 bf16x8*)(PBw + cl*80 + g*16);
    #pragma unroll
    for (int dt = 0; dt < 4; ++dt) {
      const bf16x8 bv = *(const AS3 bf16x8*)(vb + (dt*16 + cl)*64 + ((g ^ kvkey) << 4));
      accP[dt] = mfma16(ap, bv, accP[dt]);
    }
  }

  float ssum = (sa0 + sa1) + (sa2 + sa3);
  ssum += __shfl_xor(ssum, 16, 64);
  ssum += __shfl_xor(ssum, 32, 64);
  const float inv = 1.0f / ssum;

  #pragma unroll
  for (int r = 0; r < 4; ++r) {
    const float invq = __shfl(inv, g*4 + r, 64);
    const size_t row = (size_t)(b * S_LEN + q0 + w*16 + g*4 + r);
    #pragma unroll
    for (int dt = 0; dt < 4; ++dt)
      ctx[row * DM + h * KDIM + dt*16 + cl] = f2bf(accP[dt][r] * invq);
  }

  __syncthreads();

  // ================= PASS B: recompute + stream fp32 attn =================
  float* const arow = attn + ((size_t)bh * S_LEN + q0 + w*16 + cl) * S_LEN + g*4;

  for (int i = 0; i < 6; ++i) STAGE_K(i);
  for (int c = 0; c < 64; ++c) {
    STAGE_K(c + 6);
    if (w < 4) {
      if (c < 6) asm volatile("s_waitcnt vmcnt(6)"  ::: "memory");
      else       asm volatile("s_waitcnt vmcnt(18)" ::: "memory");
    }
    __builtin_amdgcn_s_barrier();
    __builtin_amdgcn_sched_barrier(0);
    AS3 const char* kb = KB + (c & 7) * 4096;
    #pragma unroll
    for (int s = 0; s < 2; ++s) {
      const bf16x8 k0 = *(const AS3 bf16x8*)(kb + s*2048 + koff0);
      const bf16x8 k1 = *(const AS3 bf16x8*)(kb + s*2048 + koff1);
      f32x4 acc = {0.f, 0.f, 0.f, 0.f};
      acc = mfma16(k0, qf0, acc);
      acc = mfma16(k1, qf1, acc);
      f32x4 p;
      p[0] = __builtin_exp2f(acc[0] * SC2) * inv;
      p[1] = __builtin_exp2f(acc[1] * SC2) * inv;
      p[2] = __builtin_exp2f(acc[2] * SC2) * inv;
      p[3] = __builtin_exp2f(acc[3] * SC2) * inv;
      *reinterpret_cast<f32x4*>(arow + c*32 + s*16) = p;
    }
  }
  #undef STAGE_KV
  #undef STAGE_K
}

// ---------------------------------------------------------------------------
extern "C" void kernel_launch(void* const* d_in, const int* in_sizes, int n_in,
                              void* d_out, int out_size, void* d_ws, size_t ws_size,
                              hipStream_t stream)
{
  const float* q_in = (const float*)d_in[0];
  const float* k_in = (const float*)d_in[1];
  const float* v_in = (const float*)d_in[2];
  const float* Wq   = (const float*)d_in[3];
  const float* bq   = (const float*)d_in[4];
  const float* Wk   = (const float*)d_in[5];
  const float* bk   = (const float*)d_in[6];
  const float* Wv   = (const float*)d_in[7];
  const float* bv   = (const float*)d_in[8];
  const float* Wo   = (const float*)d_in[9];
  const float* bo   = (const float*)d_in[10];

  unsigned short* qbf  = (unsigned short*)d_ws;
  unsigned short* kbf  = qbf  + (size_t)MTOK*DM;
  unsigned short* vbf  = kbf  + (size_t)MTOK*DM;
  unsigned short* wqbf = vbf  + (size_t)MTOK*DM;
  unsigned short* wkbf = wqbf + (size_t)DM*DM;
  unsigned short* wvbf = wkbf + (size_t)DM*DM;
  unsigned short* wobf = wvbf + (size_t)DM*DM;
  unsigned short* Qhp  = wobf + (size_t)DM*DM;    // [b,h,s,d]
  unsigned short* Khp  = Qhp  + (size_t)MTOK*DM;  // [b,h,s,d]
  unsigned short* Vtp  = Khp  + (size_t)MTOK*DM;  // [b,h,d,s]
  unsigned short* ctx  = Vtp  + (size_t)MTOK*DM;  // [b*s, h*d]

  float* out0 = (float*)d_out;
  float* attn = out0 + (size_t)MTOK*DM;

  CvtArgs ca;
  ca.src[0] = q_in; ca.dst[0] = qbf;  ca.n[0] = MTOK*DM;
  ca.src[1] = k_in; ca.dst[1] = kbf;  ca.n[1] = MTOK*DM;
  ca.src[2] = v_in; ca.dst[2] = vbf;  ca.n[2] = MTOK*DM;
  ca.src[3] = Wq;   ca.dst[3] = wqbf; ca.n[3] = DM*DM;
  ca.src[4] = Wk;   ca.dst[4] = wkbf; ca.n[4] = DM*DM;
  ca.src[5] = Wv;   ca.dst[5] = wvbf; ca.n[5] = DM*DM;
  ca.src[6] = Wo;   ca.dst[6] = wobf; ca.n[6] = DM*DM;
  cvt_f32_bf16<<<dim3(512, 7), 256, 0, stream>>>(ca);

  GemmArgs gq;
  gq.A[0] = qbf;  gq.W[0] = wqbf; gq.bias[0] = bq; gq.dst[0] = Qhp; gq.mode[0] = 0;
  gq.A[1] = kbf;  gq.W[1] = wkbf; gq.bias[1] = bk; gq.dst[1] = Khp; gq.mode[1] = 0;
  gq.A[2] = vbf;  gq.W[2] = wvbf; gq.bias[2] = bv; gq.dst[2] = Vtp; gq.mode[2] = 1;
  gemm_pipe<<<dim3(8, 32, 3), 256, 0, stream>>>(gq);

  attn_fused7<<<dim3(512), 512, 0, stream>>>(Qhp, Khp, Vtp, attn, ctx);

  GemmArgs go;
  go.A[0] = ctx; go.W[0] = wobf; go.bias[0] = bo; go.dst[0] = out0; go.mode[0] = 2;
  go.A[1] = ctx; go.W[1] = wobf; go.bias[1] = bo; go.dst[1] = out0; go.mode[1] = 2;
  go.A[2] = ctx; go.W[2] = wobf; go.bias[2] = bo; go.dst[2] = out0; go.mode[2] = 2;
  gemm_pipe<<<dim3(8, 32, 1), 256, 0, stream>>>(go);
}